// Round 26
// baseline (397.059 us; speedup 1.0000x reference)
//
#include <hip/hip_runtime.h>
#include <hip/hip_bf16.h>

#define S_LEN 4096
#define NH    16
#define DD    128
#define HD    2048
#define QB    128
#define KB    64
#define NT    (S_LEN/KB)

typedef __bf16 bf16_t;
typedef bf16_t bf16x8 __attribute__((ext_vector_type(8)));
typedef float  f32x4  __attribute__((ext_vector_type(4)));

static __device__ __forceinline__ bf16x8 pack8(float4 a, float4 b, float s) {
  bf16x8 v;
  v[0]=(bf16_t)(a.x*s); v[1]=(bf16_t)(a.y*s); v[2]=(bf16_t)(a.z*s); v[3]=(bf16_t)(a.w*s);
  v[4]=(bf16_t)(b.x*s); v[5]=(bf16_t)(b.y*s); v[6]=(bf16_t)(b.z*s); v[7]=(bf16_t)(b.w*s);
  return v;
}

static __device__ __forceinline__ void gload_lds16(const void* g, void* l) {
  __builtin_amdgcn_global_load_lds((const __attribute__((address_space(1))) void*)g,
                                   (__attribute__((address_space(3))) void*)l, 16, 0, 0);
}

// ---- fused prep: z=0 -> K frag-major tiles; z=1 -> V^T frag-major tiles ----
__global__ __launch_bounds__(256) void prep_kv(const float* __restrict__ Kg,
                                               const float* __restrict__ Vg,
                                               bf16_t* __restrict__ Kp,
                                               bf16_t* __restrict__ Vp) {
  const int kt = blockIdx.x, h = blockIdx.y, which = blockIdx.z, tid = threadIdx.x;
  const float* src = which ? Vg : Kg;
  __shared__ bf16_t tile[KB][DD + 8];
  #pragma unroll
  for (int it = 0; it < 8; ++it) {
    int lin4 = it*256 + tid;
    int r  = lin4 >> 5;
    int dc = (lin4 & 31) * 4;
    float4 a = *(const float4*)(src + (size_t)(kt*KB + r)*HD + h*DD + dc);
    tile[r][dc+0]=(bf16_t)a.x; tile[r][dc+1]=(bf16_t)a.y;
    tile[r][dc+2]=(bf16_t)a.z; tile[r][dc+3]=(bf16_t)a.w;
  }
  __syncthreads();
  if (which == 0) {
    bf16_t* out = Kp + (size_t)(h*NT + kt)*8192;
    #pragma unroll
    for (int it = 0; it < 4; ++it) {
      int cid = it*256 + tid;
      int f = cid >> 6, l = cid & 63;
      int b = f >> 2, c = f & 3;
      int row = b*16 + (l & 15);
      int d0  = c*32 + (l >> 4)*8;
      bf16x8 v = *(const bf16x8*)(&tile[row][d0]);
      *(bf16x8*)(out + (size_t)cid*8) = v;
    }
  } else {
    bf16_t* out = Vp + (size_t)(h*NT + kt)*8192;
    #pragma unroll
    for (int it = 0; it < 4; ++it) {
      int cid = it*256 + tid;
      int f = cid >> 6, l = cid & 63;
      int ks = f >> 3, db = f & 7;
      int d  = db*16 + (l & 15);
      int c0 = ks*32 + (l >> 4)*8;
      bf16x8 v;
      #pragma unroll
      for (int m = 0; m < 8; ++m) {
        int c = c0 + m;
        int k = 32*(c>>5) + 16*((c>>2)&1) + 4*((c>>3)&3) + (c&3);
        v[m] = tile[k][d];
      }
      *(bf16x8*)(out + (size_t)cid*8) = v;
    }
  }
}

// QK cluster: DST[2][4] = K-frags x qf (zero-init inside); reads base + lane*16 + imm
#define QK_COMPUTE(DST, KSBASE)                                                  \
  do {                                                                           \
    _Pragma("unroll")                                                            \
    for (int g_ = 0; g_ < 2; ++g_)                                               \
      _Pragma("unroll")                                                          \
      for (int b_ = 0; b_ < 4; ++b_) DST[g_][b_] = (f32x4){0.f,0.f,0.f,0.f};     \
    _Pragma("unroll")                                                            \
    for (int b_ = 0; b_ < 4; ++b_) {                                             \
      _Pragma("unroll")                                                          \
      for (int c_ = 0; c_ < 4; ++c_) {                                           \
        bf16x8 kb_ = *(const bf16x8*)((KSBASE) + ((b_*4 + c_) << 10));           \
        DST[0][b_] = __builtin_amdgcn_mfma_f32_16x16x32_bf16(kb_, qf[0][c_], DST[0][b_], 0, 0, 0); \
        DST[1][b_] = __builtin_amdgcn_mfma_f32_16x16x32_bf16(kb_, qf[1][c_], DST[1][b_], 0, 0, 0); \
      }                                                                          \
    }                                                                            \
  } while (0)

// hoist V fragments for one tile from LDS buffer CURX into register set VF
#define VHOIST(VF, CURX)                                                         \
  do {                                                                           \
    const char* VtB_ = (const char*)&Vt[CURX][0] + lo16;                         \
    _Pragma("unroll")                                                            \
    for (int f_ = 0; f_ < 16; ++f_) VF[f_] = *(const bf16x8*)(VtB_ + (f_ << 10)); \
  } while (0)

// softmax(SC) -> pp ; then PV from VF regs.
// LOCAL-pmax fast path: no cross-lane shuffles unless rescale needed.
#define SOFTMAX_PV(SC, VF)                                                       \
  do {                                                                           \
    bf16x8 pp[2][2];                                                             \
    _Pragma("unroll")                                                            \
    for (int g = 0; g < 2; ++g) {                                                \
      float pmax;                                                                \
      {                                                                          \
        float a0 = fmaxf(fmaxf(SC[g][0][0], SC[g][0][1]), SC[g][0][2]);          \
        float a1 = fmaxf(fmaxf(SC[g][0][3], SC[g][1][0]), SC[g][1][1]);          \
        float a2 = fmaxf(fmaxf(SC[g][1][2], SC[g][1][3]), SC[g][2][0]);          \
        float a3 = fmaxf(fmaxf(SC[g][2][1], SC[g][2][2]), SC[g][2][3]);          \
        float a4 = fmaxf(fmaxf(SC[g][3][0], SC[g][3][1]), SC[g][3][2]);          \
        float b0 = fmaxf(fmaxf(a0, a1), a2);                                     \
        float b1 = fmaxf(fmaxf(a3, a4), SC[g][3][3]);                            \
        pmax = fmaxf(b0, b1);   /* LANE-LOCAL max (16 own scores) */             \
      }                                                                          \
      if (!__all(pmax - m_run[g] <= 8.0f)) {                                     \
        /* rare path: true row max via cross-lane, then rescale */               \
        pmax = fmaxf(pmax, __shfl_xor(pmax, 16));                                \
        pmax = fmaxf(pmax, __shfl_xor(pmax, 32));                                \
        float mnew  = fmaxf(m_run[g], pmax);                                     \
        float alpha = exp2f(m_run[g] - mnew);                                    \
        m_run[g] = mnew;                                                         \
        _Pragma("unroll")                                                        \
        for (int i = 0; i < 8; ++i) {                                            \
          _Pragma("unroll")                                                      \
          for (int r = 0; r < 4; ++r) acc[g][i][r] *= alpha;                     \
        }                                                                        \
        _Pragma("unroll")                                                        \
        for (int r = 0; r < 4; ++r) acc_l[g][r] *= alpha;                        \
      }                                                                          \
      _Pragma("unroll")                                                          \
      for (int b_ = 0; b_ < 4; ++b_) {                                           \
        _Pragma("unroll")                                                        \
        for (int r = 0; r < 4; ++r) {                                            \
          float p = exp2f(SC[g][b_][r] - m_run[g]);   /* bounded by 2^8 */       \
          pp[g][b_ >> 1][(b_ & 1)*4 + r] = (bf16_t)p;                            \
        }                                                                        \
      }                                                                          \
    }                                                                            \
    __builtin_amdgcn_s_setprio(1);                                               \
    _Pragma("unroll")                                                            \
    for (int ks = 0; ks < 2; ++ks) {                                             \
      acc_l[0] = __builtin_amdgcn_mfma_f32_16x16x32_bf16(onesf, pp[0][ks], acc_l[0], 0, 0, 0); \
      acc_l[1] = __builtin_amdgcn_mfma_f32_16x16x32_bf16(onesf, pp[1][ks], acc_l[1], 0, 0, 0); \
      _Pragma("unroll")                                                          \
      for (int db = 0; db < 8; ++db) {                                           \
        bf16x8 va = VF[ks*8 + db];                                               \
        acc[0][db] = __builtin_amdgcn_mfma_f32_16x16x32_bf16(va, pp[0][ks], acc[0][db], 0, 0, 0); \
        acc[1][db] = __builtin_amdgcn_mfma_f32_16x16x32_bf16(va, pp[1][ks], acc[1][db], 0, 0, 0); \
      }                                                                          \
    }                                                                            \
    __builtin_amdgcn_s_setprio(0);                                               \
  } while (0)

// one pipeline stage; CUR = parity of KT (compile-time literal).
// Pipelined V-hoist: VFC (hoisted last stage) feeds PV(KT); VFN is hoisted
// here for tile KT+1, overlapping with issue + QK + SM/PV.
//   sync -> barrier -> issue(KT+2 -> buf[CUR]) -> hoist VFN from buf[CUR^1]
//        -> QK(KT+1) -> SM+PV(KT, VFC)
#define BODY(SCUR, SNXT, VFC, VFN, KT, CUR)                                      \
  do {                                                                           \
    asm volatile("s_waitcnt vmcnt(0) lgkmcnt(0)" ::: "memory");                  \
    __builtin_amdgcn_sched_barrier(0);                                           \
    __builtin_amdgcn_s_barrier();                                                \
    if ((KT) + 2 < NT) issue((KT) + 2, CUR);                                     \
    VHOIST(VFN, (CUR) ^ 1);                                                      \
    {                                                                            \
      const char* KsB_ = (const char*)&Ks[(CUR) ^ 1][0] + lo16;                  \
      QK_COMPUTE(SNXT, KsB_);                                                    \
    }                                                                            \
    SOFTMAX_PV(SCUR, VFC);                                                       \
  } while (0)

__global__ __launch_bounds__(256, 2) void attn_fwd(const float* __restrict__ Qg,
                                                   const bf16_t* __restrict__ Kp,
                                                   const bf16_t* __restrict__ Vp,
                                                   float* __restrict__ Og) {
  // chunked XCD swizzle: 512 blocks, XCD x owns logical [x*64, x*64+64) = 2 heads
  const int phys = blockIdx.x;
  const int logical = (phys & 7) * 64 + (phys >> 3);
  const int h  = logical >> 5;
  const int qt = logical & 31;       // q-tile of 128 rows
  const int tid  = threadIdx.x;
  const int wid  = tid >> 6;         // 0..3
  const int lane = tid & 63;
  const int l16  = lane & 15;
  const int lg   = lane >> 4;
  const int lo16 = lane * 16;

  __shared__ alignas(16) bf16_t Ks[2][8192];   // 16KB each, frag-major
  __shared__ alignas(16) bf16_t Vt[2][8192];   // 16KB each, frag-major

  // ---- Q fragments for 2 q-groups (B-operand of swapped QK^T) ----
  const float qs = 0.08838834764831845f * 1.4426950408889634f;
  bf16x8 qf[2][4];
  #pragma unroll
  for (int g = 0; g < 2; ++g) {
    const int qrow = qt*QB + wid*32 + g*16 + l16;
    const float* qp = Qg + (size_t)qrow*HD + h*DD + lg*8;
    #pragma unroll
    for (int c = 0; c < 4; ++c) {
      float4 a = *(const float4*)(qp + c*32);
      float4 b = *(const float4*)(qp + c*32 + 4);
      qf[g][c] = pack8(a, b, qs);
    }
  }
  bf16x8 onesf;
  #pragma unroll
  for (int j = 0; j < 8; ++j) onesf[j] = (bf16_t)1.0f;
  asm volatile("" ::: "memory");

  // ---- staging: pure linear global->LDS DMA (8x16B per thread per tile) ----
  const int lo = tid*16;
  auto issue = [&](int kt, int b) {
    const char* kg = (const char*)(Kp + (size_t)(h*NT + kt)*8192);
    const char* vg = (const char*)(Vp + (size_t)(h*NT + kt)*8192);
    char* kl = (char*)&Ks[b][0];
    char* vl = (char*)&Vt[b][0];
    #pragma unroll
    for (int p = 0; p < 4; ++p) gload_lds16(kg + lo + p*4096, kl + lo + p*4096);
    #pragma unroll
    for (int p = 0; p < 4; ++p) gload_lds16(vg + lo + p*4096, vl + lo + p*4096);
  };

  f32x4 acc[2][8];
  f32x4 acc_l[2];
  #pragma unroll
  for (int g = 0; g < 2; ++g) {
    #pragma unroll
    for (int i = 0; i < 8; ++i) acc[g][i] = (f32x4){0.f,0.f,0.f,0.f};
    acc_l[g] = (f32x4){0.f,0.f,0.f,0.f};
  }
  float m_run[2] = {-__builtin_inff(), -__builtin_inff()};

  issue(0, 0);
  issue(1, 1);
  asm volatile("s_waitcnt vmcnt(8)" ::: "memory");  // tile 0 arrived (8 of tile1 in flight)
  __builtin_amdgcn_s_barrier();
  __builtin_amdgcn_sched_barrier(0);

  // prologue: hoist vfA (tile 0) + QK(0) -> scA
  f32x4 scA[2][4], scB[2][4];
  bf16x8 vfA[16], vfB[16];
  VHOIST(vfA, 0);
  {
    const char* KsB = (const char*)&Ks[0][0] + lo16;
    QK_COMPUTE(scA, KsB);
  }

  // NT-1 = 63 pipeline stages: 31 ping-pong pairs (kt=0..61) + 1 (kt=62), then tail
  for (int kt = 0; kt < NT-2; kt += 2) {
    BODY(scA, scB, vfA, vfB, kt,   0);
    BODY(scB, scA, vfB, vfA, kt+1, 1);
  }
  BODY(scA, scB, vfA, vfB, NT-2, 0);   // kt=62: hoist vfB (tile 63), QK(63)->scB, PV(62,vfA)

  // ---- tail tile NT-1 = 63: softmax + PV from scB with vfB (already hoisted) ----
  asm volatile("s_waitcnt lgkmcnt(0)" ::: "memory");
  SOFTMAX_PV(scB, vfB);

  // ---- epilogue: normalize, store O (lane: q=g*16+l16, d=db*16+lg*4+r) ----
  #pragma unroll
  for (int g = 0; g < 2; ++g) {
    const int qrow = qt*QB + wid*32 + g*16 + l16;
    const float inv = 1.0f / acc_l[g][0];
    float* op = Og + (size_t)qrow*HD + h*DD + lg*4;
    #pragma unroll
    for (int db = 0; db < 8; ++db) {
      float4 o;
      o.x = acc[g][db][0]*inv; o.y = acc[g][db][1]*inv;
      o.z = acc[g][db][2]*inv; o.w = acc[g][db][3]*inv;
      *(float4*)(op + db*16) = o;
    }
  }
}

extern "C" void kernel_launch(void* const* d_in, const int* in_sizes, int n_in,
                              void* d_out, int out_size, void* d_ws, size_t ws_size,
                              hipStream_t stream) {
  const float* Q = (const float*)d_in[0];
  const float* K = (const float*)d_in[1];
  const float* V = (const float*)d_in[2];
  float* O = (float*)d_out;
  bf16_t* Kp = (bf16_t*)d_ws;                       // 16.78 MB
  bf16_t* Vp = Kp + (size_t)NH*S_LEN*DD;            // 16.78 MB
  prep_kv<<<dim3(NT, NH, 2), 256, 0, stream>>>(K, V, Kp, Vp);
  attn_fwd<<<dim3(512), 256, 0, stream>>>(Q, Kp, Vp, O);
}

// Round 27
// 169.184 us; speedup vs baseline: 2.3469x; 2.3469x over previous
//
#include <hip/hip_runtime.h>
#include <hip/hip_bf16.h>

#define S_LEN 4096
#define NH    16
#define DD    128
#define HD    2048
#define QB    128
#define KB    64
#define NT    (S_LEN/KB)

typedef __bf16 bf16_t;
typedef bf16_t bf16x8 __attribute__((ext_vector_type(8)));
typedef float  f32x4  __attribute__((ext_vector_type(4)));

static __device__ __forceinline__ bf16x8 pack8(float4 a, float4 b, float s) {
  bf16x8 v;
  v[0]=(bf16_t)(a.x*s); v[1]=(bf16_t)(a.y*s); v[2]=(bf16_t)(a.z*s); v[3]=(bf16_t)(a.w*s);
  v[4]=(bf16_t)(b.x*s); v[5]=(bf16_t)(b.y*s); v[6]=(bf16_t)(b.z*s); v[7]=(bf16_t)(b.w*s);
  return v;
}

static __device__ __forceinline__ void gload_lds16(const void* g, void* l) {
  __builtin_amdgcn_global_load_lds((const __attribute__((address_space(1))) void*)g,
                                   (__attribute__((address_space(3))) void*)l, 16, 0, 0);
}

// ---- fused prep: z=0 -> K frag-major tiles; z=1 -> V^T frag-major tiles ----
__global__ __launch_bounds__(256) void prep_kv(const float* __restrict__ Kg,
                                               const float* __restrict__ Vg,
                                               bf16_t* __restrict__ Kp,
                                               bf16_t* __restrict__ Vp) {
  const int kt = blockIdx.x, h = blockIdx.y, which = blockIdx.z, tid = threadIdx.x;
  const float* src = which ? Vg : Kg;
  __shared__ bf16_t tile[KB][DD + 8];
  #pragma unroll
  for (int it = 0; it < 8; ++it) {
    int lin4 = it*256 + tid;
    int r  = lin4 >> 5;
    int dc = (lin4 & 31) * 4;
    float4 a = *(const float4*)(src + (size_t)(kt*KB + r)*HD + h*DD + dc);
    tile[r][dc+0]=(bf16_t)a.x; tile[r][dc+1]=(bf16_t)a.y;
    tile[r][dc+2]=(bf16_t)a.z; tile[r][dc+3]=(bf16_t)a.w;
  }
  __syncthreads();
  if (which == 0) {
    bf16_t* out = Kp + (size_t)(h*NT + kt)*8192;
    #pragma unroll
    for (int it = 0; it < 4; ++it) {
      int cid = it*256 + tid;
      int f = cid >> 6, l = cid & 63;
      int b = f >> 2, c = f & 3;
      int row = b*16 + (l & 15);
      int d0  = c*32 + (l >> 4)*8;
      bf16x8 v = *(const bf16x8*)(&tile[row][d0]);
      *(bf16x8*)(out + (size_t)cid*8) = v;
    }
  } else {
    bf16_t* out = Vp + (size_t)(h*NT + kt)*8192;
    #pragma unroll
    for (int it = 0; it < 4; ++it) {
      int cid = it*256 + tid;
      int f = cid >> 6, l = cid & 63;
      int ks = f >> 3, db = f & 7;
      int d  = db*16 + (l & 15);
      int c0 = ks*32 + (l >> 4)*8;
      bf16x8 v;
      #pragma unroll
      for (int m = 0; m < 8; ++m) {
        int c = c0 + m;
        int k = 32*(c>>5) + 16*((c>>2)&1) + 4*((c>>3)&3) + (c&3);
        v[m] = tile[k][d];
      }
      *(bf16x8*)(out + (size_t)cid*8) = v;
    }
  }
}

// QK cluster: DST[2][4] = K-frags x qf (zero-init inside); reads base + lane*16 + imm
#define QK_COMPUTE(DST, KSBASE)                                                  \
  do {                                                                           \
    _Pragma("unroll")                                                            \
    for (int g_ = 0; g_ < 2; ++g_)                                               \
      _Pragma("unroll")                                                          \
      for (int b_ = 0; b_ < 4; ++b_) DST[g_][b_] = (f32x4){0.f,0.f,0.f,0.f};     \
    _Pragma("unroll")                                                            \
    for (int b_ = 0; b_ < 4; ++b_) {                                             \
      _Pragma("unroll")                                                          \
      for (int c_ = 0; c_ < 4; ++c_) {                                           \
        bf16x8 kb_ = *(const bf16x8*)((KSBASE) + ((b_*4 + c_) << 10));           \
        DST[0][b_] = __builtin_amdgcn_mfma_f32_16x16x32_bf16(kb_, qf[0][c_], DST[0][b_], 0, 0, 0); \
        DST[1][b_] = __builtin_amdgcn_mfma_f32_16x16x32_bf16(kb_, qf[1][c_], DST[1][b_], 0, 0, 0); \
      }                                                                          \
    }                                                                            \
  } while (0)

// softmax(SC) -> pp ; then PV from vf regs.
// LOCAL-pmax fast path: no cross-lane shuffles unless rescale needed.
#define SOFTMAX_PV(SC)                                                           \
  do {                                                                           \
    bf16x8 pp[2][2];                                                             \
    _Pragma("unroll")                                                            \
    for (int g = 0; g < 2; ++g) {                                                \
      float pmax;                                                                \
      {                                                                          \
        float a0 = fmaxf(fmaxf(SC[g][0][0], SC[g][0][1]), SC[g][0][2]);          \
        float a1 = fmaxf(fmaxf(SC[g][0][3], SC[g][1][0]), SC[g][1][1]);          \
        float a2 = fmaxf(fmaxf(SC[g][1][2], SC[g][1][3]), SC[g][2][0]);          \
        float a3 = fmaxf(fmaxf(SC[g][2][1], SC[g][2][2]), SC[g][2][3]);          \
        float a4 = fmaxf(fmaxf(SC[g][3][0], SC[g][3][1]), SC[g][3][2]);          \
        float b0 = fmaxf(fmaxf(a0, a1), a2);                                     \
        float b1 = fmaxf(fmaxf(a3, a4), SC[g][3][3]);                            \
        pmax = fmaxf(b0, b1);   /* LANE-LOCAL max (16 own scores) */             \
      }                                                                          \
      if (!__all(pmax - m_run[g] <= 8.0f)) {                                     \
        /* rare path: true row max via cross-lane, then rescale */               \
        pmax = fmaxf(pmax, __shfl_xor(pmax, 16));                                \
        pmax = fmaxf(pmax, __shfl_xor(pmax, 32));                                \
        float mnew  = fmaxf(m_run[g], pmax);                                     \
        float alpha = exp2f(m_run[g] - mnew);                                    \
        m_run[g] = mnew;                                                         \
        _Pragma("unroll")                                                        \
        for (int i = 0; i < 8; ++i) {                                            \
          _Pragma("unroll")                                                      \
          for (int r = 0; r < 4; ++r) acc[g][i][r] *= alpha;                     \
        }                                                                        \
        _Pragma("unroll")                                                        \
        for (int r = 0; r < 4; ++r) acc_l[g][r] *= alpha;                        \
      }                                                                          \
      _Pragma("unroll")                                                          \
      for (int b_ = 0; b_ < 4; ++b_) {                                           \
        _Pragma("unroll")                                                        \
        for (int r = 0; r < 4; ++r) {                                            \
          float p = exp2f(SC[g][b_][r] - m_run[g]);   /* bounded by 2^8 */       \
          pp[g][b_ >> 1][(b_ & 1)*4 + r] = (bf16_t)p;                            \
        }                                                                        \
      }                                                                          \
    }                                                                            \
    __builtin_amdgcn_s_setprio(1);                                               \
    _Pragma("unroll")                                                            \
    for (int ks = 0; ks < 2; ++ks) {                                             \
      acc_l[0] = __builtin_amdgcn_mfma_f32_16x16x32_bf16(onesf, pp[0][ks], acc_l[0], 0, 0, 0); \
      acc_l[1] = __builtin_amdgcn_mfma_f32_16x16x32_bf16(onesf, pp[1][ks], acc_l[1], 0, 0, 0); \
      _Pragma("unroll")                                                          \
      for (int db = 0; db < 8; ++db) {                                           \
        bf16x8 va = vf[ks*8 + db];                                               \
        acc[0][db] = __builtin_amdgcn_mfma_f32_16x16x32_bf16(va, pp[0][ks], acc[0][db], 0, 0, 0); \
        acc[1][db] = __builtin_amdgcn_mfma_f32_16x16x32_bf16(va, pp[1][ks], acc[1][db], 0, 0, 0); \
      }                                                                          \
    }                                                                            \
    __builtin_amdgcn_s_setprio(0);                                               \
  } while (0)

// one pipeline stage, CUR is a compile-time literal (buffer parity of KT):
//   V-hoist(KT) from buf[CUR] -> single sync -> issue(KT+2) -> QK(KT+1)->SNXT || SM+PV(KT) from SCUR
// NOTE: no sched_barrier after issue -- the 8 DMA issues may interleave with
// QK's ds_reads/MFMAs (safe: VMEM ordering vs barrier is program-order).
#define BODY(SCUR, SNXT, KT, CUR)                                                \
  do {                                                                           \
    bf16x8 vf[16];                                                               \
    {                                                                            \
      const char* VtB_ = (const char*)&Vt[CUR][0] + lo16;                        \
      _Pragma("unroll")                                                          \
      for (int f_ = 0; f_ < 16; ++f_) vf[f_] = *(const bf16x8*)(VtB_ + (f_ << 10)); \
    }                                                                            \
    asm volatile("s_waitcnt vmcnt(0) lgkmcnt(0)" ::: "memory");                  \
    __builtin_amdgcn_sched_barrier(0);                                           \
    __builtin_amdgcn_s_barrier();                                                \
    if ((KT) + 2 < NT) issue((KT) + 2, CUR);                                     \
    {                                                                            \
      const char* KsB_ = (const char*)&Ks[(CUR) ^ 1][0] + lo16;                  \
      QK_COMPUTE(SNXT, KsB_);                                                    \
    }                                                                            \
    SOFTMAX_PV(SCUR);                                                            \
  } while (0)

__global__ __launch_bounds__(256, 2) void attn_fwd(const float* __restrict__ Qg,
                                                   const bf16_t* __restrict__ Kp,
                                                   const bf16_t* __restrict__ Vp,
                                                   float* __restrict__ Og) {
  // chunked XCD swizzle: 512 blocks, XCD x owns logical [x*64, x*64+64) = 2 heads
  const int phys = blockIdx.x;
  const int logical = (phys & 7) * 64 + (phys >> 3);
  const int h  = logical >> 5;
  const int qt = logical & 31;       // q-tile of 128 rows
  const int tid  = threadIdx.x;
  const int wid  = tid >> 6;         // 0..3
  const int lane = tid & 63;
  const int l16  = lane & 15;
  const int lg   = lane >> 4;
  const int lo16 = lane * 16;

  __shared__ alignas(16) bf16_t Ks[2][8192];   // 16KB each, frag-major
  __shared__ alignas(16) bf16_t Vt[2][8192];   // 16KB each, frag-major

  // ---- Q fragments for 2 q-groups (B-operand of swapped QK^T) ----
  const float qs = 0.08838834764831845f * 1.4426950408889634f;
  bf16x8 qf[2][4];
  #pragma unroll
  for (int g = 0; g < 2; ++g) {
    const int qrow = qt*QB + wid*32 + g*16 + l16;
    const float* qp = Qg + (size_t)qrow*HD + h*DD + lg*8;
    #pragma unroll
    for (int c = 0; c < 4; ++c) {
      float4 a = *(const float4*)(qp + c*32);
      float4 b = *(const float4*)(qp + c*32 + 4);
      qf[g][c] = pack8(a, b, qs);
    }
  }
  bf16x8 onesf;
  #pragma unroll
  for (int j = 0; j < 8; ++j) onesf[j] = (bf16_t)1.0f;
  asm volatile("" ::: "memory");

  // ---- staging: pure linear global->LDS DMA (8x16B per thread per tile) ----
  const int lo = tid*16;
  auto issue = [&](int kt, int b) {
    const char* kg = (const char*)(Kp + (size_t)(h*NT + kt)*8192);
    const char* vg = (const char*)(Vp + (size_t)(h*NT + kt)*8192);
    char* kl = (char*)&Ks[b][0];
    char* vl = (char*)&Vt[b][0];
    #pragma unroll
    for (int p = 0; p < 4; ++p) gload_lds16(kg + lo + p*4096, kl + lo + p*4096);
    #pragma unroll
    for (int p = 0; p < 4; ++p) gload_lds16(vg + lo + p*4096, vl + lo + p*4096);
  };

  f32x4 acc[2][8];
  f32x4 acc_l[2];
  #pragma unroll
  for (int g = 0; g < 2; ++g) {
    #pragma unroll
    for (int i = 0; i < 8; ++i) acc[g][i] = (f32x4){0.f,0.f,0.f,0.f};
    acc_l[g] = (f32x4){0.f,0.f,0.f,0.f};
  }
  float m_run[2] = {-__builtin_inff(), -__builtin_inff()};

  issue(0, 0);
  issue(1, 1);
  asm volatile("s_waitcnt vmcnt(8)" ::: "memory");  // tile 0 arrived (8 of tile1 in flight)
  __builtin_amdgcn_s_barrier();
  __builtin_amdgcn_sched_barrier(0);

  // prologue QK(0) -> scA
  f32x4 scA[2][4], scB[2][4];
  {
    const char* KsB = (const char*)&Ks[0][0] + lo16;
    QK_COMPUTE(scA, KsB);
  }

  // NT-1 = 63 pipeline stages: 31 ping-pong pairs (kt=0..61) + 1 (kt=62), then tail
  for (int kt = 0; kt < NT-2; kt += 2) {
    BODY(scA, scB, kt,   0);
    BODY(scB, scA, kt+1, 1);
  }
  BODY(scA, scB, NT-2, 0);   // kt = 62: QK(63)->scB, SM+PV(62)

  // ---- tail tile NT-1 = 63: V hoist from buf[1] + softmax + PV (no more DMA) ----
  {
    bf16x8 vf[16];
    const char* VtB = (const char*)&Vt[1][0] + lo16;
    #pragma unroll
    for (int f = 0; f < 16; ++f) vf[f] = *(const bf16x8*)(VtB + (f << 10));
    SOFTMAX_PV(scB);
  }

  // ---- epilogue: normalize, store O (lane: q=g*16+l16, d=db*16+lg*4+r) ----
  #pragma unroll
  for (int g = 0; g < 2; ++g) {
    const int qrow = qt*QB + wid*32 + g*16 + l16;
    const float inv = 1.0f / acc_l[g][0];
    float* op = Og + (size_t)qrow*HD + h*DD + lg*4;
    #pragma unroll
    for (int db = 0; db < 8; ++db) {
      float4 o;
      o.x = acc[g][db][0]*inv; o.y = acc[g][db][1]*inv;
      o.z = acc[g][db][2]*inv; o.w = acc[g][db][3]*inv;
      *(float4*)(op + db*16) = o;
    }
  }
}

extern "C" void kernel_launch(void* const* d_in, const int* in_sizes, int n_in,
                              void* d_out, int out_size, void* d_ws, size_t ws_size,
                              hipStream_t stream) {
  const float* Q = (const float*)d_in[0];
  const float* K = (const float*)d_in[1];
  const float* V = (const float*)d_in[2];
  float* O = (float*)d_out;
  bf16_t* Kp = (bf16_t*)d_ws;                       // 16.78 MB
  bf16_t* Vp = Kp + (size_t)NH*S_LEN*DD;            // 16.78 MB
  prep_kv<<<dim3(NT, NH, 2), 256, 0, stream>>>(K, V, Kp, Vp);
  attn_fwd<<<dim3(512), 256, 0, stream>>>(Q, Kp, Vp, O);
}

// Round 28
// 167.208 us; speedup vs baseline: 2.3746x; 1.0118x over previous
//
#include <hip/hip_runtime.h>
#include <hip/hip_bf16.h>

#define S_LEN 4096
#define NH    16
#define DD    128
#define HD    2048
#define QB    128
#define KB    64
#define NT    (S_LEN/KB)

typedef __bf16 bf16_t;
typedef bf16_t bf16x8 __attribute__((ext_vector_type(8)));
typedef float  f32x4  __attribute__((ext_vector_type(4)));

static __device__ __forceinline__ bf16x8 pack8(float4 a, float4 b, float s) {
  bf16x8 v;
  v[0]=(bf16_t)(a.x*s); v[1]=(bf16_t)(a.y*s); v[2]=(bf16_t)(a.z*s); v[3]=(bf16_t)(a.w*s);
  v[4]=(bf16_t)(b.x*s); v[5]=(bf16_t)(b.y*s); v[6]=(bf16_t)(b.z*s); v[7]=(bf16_t)(b.w*s);
  return v;
}

static __device__ __forceinline__ void gload_lds16(const void* g, void* l) {
  __builtin_amdgcn_global_load_lds((const __attribute__((address_space(1))) void*)g,
                                   (__attribute__((address_space(3))) void*)l, 16, 0, 0);
}

// ---- fused prep: z=0 -> K frag-major tiles; z=1 -> V^T frag-major tiles ----
__global__ __launch_bounds__(256) void prep_kv(const float* __restrict__ Kg,
                                               const float* __restrict__ Vg,
                                               bf16_t* __restrict__ Kp,
                                               bf16_t* __restrict__ Vp) {
  const int kt = blockIdx.x, h = blockIdx.y, which = blockIdx.z, tid = threadIdx.x;
  const float* src = which ? Vg : Kg;
  __shared__ bf16_t tile[KB][DD + 8];
  #pragma unroll
  for (int it = 0; it < 8; ++it) {
    int lin4 = it*256 + tid;
    int r  = lin4 >> 5;
    int dc = (lin4 & 31) * 4;
    float4 a = *(const float4*)(src + (size_t)(kt*KB + r)*HD + h*DD + dc);
    tile[r][dc+0]=(bf16_t)a.x; tile[r][dc+1]=(bf16_t)a.y;
    tile[r][dc+2]=(bf16_t)a.z; tile[r][dc+3]=(bf16_t)a.w;
  }
  __syncthreads();
  if (which == 0) {
    bf16_t* out = Kp + (size_t)(h*NT + kt)*8192;
    #pragma unroll
    for (int it = 0; it < 4; ++it) {
      int cid = it*256 + tid;
      int f = cid >> 6, l = cid & 63;
      int b = f >> 2, c = f & 3;
      int row = b*16 + (l & 15);
      int d0  = c*32 + (l >> 4)*8;
      bf16x8 v = *(const bf16x8*)(&tile[row][d0]);
      *(bf16x8*)(out + (size_t)cid*8) = v;
    }
  } else {
    bf16_t* out = Vp + (size_t)(h*NT + kt)*8192;
    #pragma unroll
    for (int it = 0; it < 4; ++it) {
      int cid = it*256 + tid;
      int f = cid >> 6, l = cid & 63;
      int ks = f >> 3, db = f & 7;
      int d  = db*16 + (l & 15);
      int c0 = ks*32 + (l >> 4)*8;
      bf16x8 v;
      #pragma unroll
      for (int m = 0; m < 8; ++m) {
        int c = c0 + m;
        int k = 32*(c>>5) + 16*((c>>2)&1) + 4*((c>>3)&3) + (c&3);
        v[m] = tile[k][d];
      }
      *(bf16x8*)(out + (size_t)cid*8) = v;
    }
  }
}

// QK cluster: DST[2][4] = K-frags x qf (zero-init inside); reads base + lane*16 + imm
#define QK_COMPUTE(DST, KSBASE)                                                  \
  do {                                                                           \
    _Pragma("unroll")                                                            \
    for (int g_ = 0; g_ < 2; ++g_)                                               \
      _Pragma("unroll")                                                          \
      for (int b_ = 0; b_ < 4; ++b_) DST[g_][b_] = (f32x4){0.f,0.f,0.f,0.f};     \
    _Pragma("unroll")                                                            \
    for (int b_ = 0; b_ < 4; ++b_) {                                             \
      _Pragma("unroll")                                                          \
      for (int c_ = 0; c_ < 4; ++c_) {                                           \
        bf16x8 kb_ = *(const bf16x8*)((KSBASE) + ((b_*4 + c_) << 10));           \
        DST[0][b_] = __builtin_amdgcn_mfma_f32_16x16x32_bf16(kb_, qf[0][c_], DST[0][b_], 0, 0, 0); \
        DST[1][b_] = __builtin_amdgcn_mfma_f32_16x16x32_bf16(kb_, qf[1][c_], DST[1][b_], 0, 0, 0); \
      }                                                                          \
    }                                                                            \
  } while (0)

// softmax for ONE q-group (SC row G) -> pp0/pp1 fragments
#define SOFTMAX_G(SC, G, PP0, PP1)                                               \
  do {                                                                           \
    float pmax;                                                                  \
    {                                                                            \
      float a0 = fmaxf(fmaxf(SC[G][0][0], SC[G][0][1]), SC[G][0][2]);            \
      float a1 = fmaxf(fmaxf(SC[G][0][3], SC[G][1][0]), SC[G][1][1]);            \
      float a2 = fmaxf(fmaxf(SC[G][1][2], SC[G][1][3]), SC[G][2][0]);            \
      float a3 = fmaxf(fmaxf(SC[G][2][1], SC[G][2][2]), SC[G][2][3]);            \
      float a4 = fmaxf(fmaxf(SC[G][3][0], SC[G][3][1]), SC[G][3][2]);            \
      float b0 = fmaxf(fmaxf(a0, a1), a2);                                       \
      float b1 = fmaxf(fmaxf(a3, a4), SC[G][3][3]);                              \
      pmax = fmaxf(b0, b1);   /* LANE-LOCAL max (16 own scores) */               \
    }                                                                            \
    if (!__all(pmax - m_run[G] <= 8.0f)) {                                       \
      /* rare path: true row max via cross-lane, then rescale */                 \
      pmax = fmaxf(pmax, __shfl_xor(pmax, 16));                                  \
      pmax = fmaxf(pmax, __shfl_xor(pmax, 32));                                  \
      float mnew  = fmaxf(m_run[G], pmax);                                       \
      float alpha = exp2f(m_run[G] - mnew);                                      \
      m_run[G] = mnew;                                                           \
      _Pragma("unroll")                                                          \
      for (int i = 0; i < 8; ++i) {                                              \
        _Pragma("unroll")                                                        \
        for (int r = 0; r < 4; ++r) acc[G][i][r] *= alpha;                       \
      }                                                                          \
      _Pragma("unroll")                                                          \
      for (int r = 0; r < 4; ++r) acc_l[G][r] *= alpha;                          \
    }                                                                            \
    _Pragma("unroll")                                                            \
    for (int b_ = 0; b_ < 4; ++b_) {                                             \
      _Pragma("unroll")                                                          \
      for (int r = 0; r < 4; ++r) {                                              \
        float p = exp2f(SC[G][b_][r] - m_run[G]);   /* bounded by 2^8 */         \
        if (b_ < 2) PP0[b_*4 + r] = (bf16_t)p; else PP1[(b_-2)*4 + r] = (bf16_t)p; \
      }                                                                          \
    }                                                                            \
  } while (0)

// PV for ONE q-group G from fragments PP0/PP1 and vf regs (17 MFMA)
#define PV_G(G, PP0, PP1)                                                        \
  do {                                                                           \
    __builtin_amdgcn_s_setprio(1);                                               \
    acc_l[G] = __builtin_amdgcn_mfma_f32_16x16x32_bf16(onesf, PP0, acc_l[G], 0, 0, 0); \
    _Pragma("unroll")                                                            \
    for (int db = 0; db < 8; ++db)                                               \
      acc[G][db] = __builtin_amdgcn_mfma_f32_16x16x32_bf16(vf[db], PP0, acc[G][db], 0, 0, 0); \
    acc_l[G] = __builtin_amdgcn_mfma_f32_16x16x32_bf16(onesf, PP1, acc_l[G], 0, 0, 0); \
    _Pragma("unroll")                                                            \
    for (int db = 0; db < 8; ++db)                                               \
      acc[G][db] = __builtin_amdgcn_mfma_f32_16x16x32_bf16(vf[8 + db], PP1, acc[G][db], 0, 0, 0); \
    __builtin_amdgcn_s_setprio(0);                                               \
  } while (0)

// interleaved: softmax(g0) -> [ PV(g0) || softmax(g1) ] -> PV(g1)
#define SOFTMAX_PV(SC)                                                           \
  do {                                                                           \
    bf16x8 pa0, pa1, pb0, pb1;                                                   \
    SOFTMAX_G(SC, 0, pa0, pa1);                                                  \
    SOFTMAX_G(SC, 1, pb0, pb1);                                                  \
    PV_G(0, pa0, pa1);                                                           \
    PV_G(1, pb0, pb1);                                                           \
  } while (0)

// one pipeline stage, CUR is a compile-time literal (buffer parity of KT):
//   V-hoist(KT) from buf[CUR] -> single sync -> issue(KT+2) -> QK(KT+1)->SNXT || SM+PV(KT) from SCUR
#define BODY(SCUR, SNXT, KT, CUR)                                                \
  do {                                                                           \
    bf16x8 vf[16];                                                               \
    {                                                                            \
      const char* VtB_ = (const char*)&Vt[CUR][0] + lo16;                        \
      _Pragma("unroll")                                                          \
      for (int f_ = 0; f_ < 16; ++f_) vf[f_] = *(const bf16x8*)(VtB_ + (f_ << 10)); \
    }                                                                            \
    asm volatile("s_waitcnt vmcnt(0) lgkmcnt(0)" ::: "memory");                  \
    __builtin_amdgcn_sched_barrier(0);                                           \
    __builtin_amdgcn_s_barrier();                                                \
    if ((KT) + 2 < NT) issue((KT) + 2, CUR);                                     \
    {                                                                            \
      const char* KsB_ = (const char*)&Ks[(CUR) ^ 1][0] + lo16;                  \
      QK_COMPUTE(SNXT, KsB_);                                                    \
    }                                                                            \
    SOFTMAX_PV(SCUR);                                                            \
  } while (0)

__global__ __launch_bounds__(256, 2) void attn_fwd(const float* __restrict__ Qg,
                                                   const bf16_t* __restrict__ Kp,
                                                   const bf16_t* __restrict__ Vp,
                                                   float* __restrict__ Og) {
  // chunked XCD swizzle: 512 blocks, XCD x owns logical [x*64, x*64+64) = 2 heads
  const int phys = blockIdx.x;
  const int logical = (phys & 7) * 64 + (phys >> 3);
  const int h  = logical >> 5;
  const int qt = logical & 31;       // q-tile of 128 rows
  const int tid  = threadIdx.x;
  const int wid  = tid >> 6;         // 0..3
  const int lane = tid & 63;
  const int l16  = lane & 15;
  const int lg   = lane >> 4;
  const int lo16 = lane * 16;

  __shared__ alignas(16) bf16_t Ks[2][8192];   // 16KB each, frag-major
  __shared__ alignas(16) bf16_t Vt[2][8192];   // 16KB each, frag-major

  // ---- Q fragments for 2 q-groups (B-operand of swapped QK^T) ----
  const float qs = 0.08838834764831845f * 1.4426950408889634f;
  bf16x8 qf[2][4];
  #pragma unroll
  for (int g = 0; g < 2; ++g) {
    const int qrow = qt*QB + wid*32 + g*16 + l16;
    const float* qp = Qg + (size_t)qrow*HD + h*DD + lg*8;
    #pragma unroll
    for (int c = 0; c < 4; ++c) {
      float4 a = *(const float4*)(qp + c*32);
      float4 b = *(const float4*)(qp + c*32 + 4);
      qf[g][c] = pack8(a, b, qs);
    }
  }
  bf16x8 onesf;
  #pragma unroll
  for (int j = 0; j < 8; ++j) onesf[j] = (bf16_t)1.0f;
  asm volatile("" ::: "memory");

  // ---- staging: pure linear global->LDS DMA (8x16B per thread per tile) ----
  const int lo = tid*16;
  auto issue = [&](int kt, int b) {
    const char* kg = (const char*)(Kp + (size_t)(h*NT + kt)*8192);
    const char* vg = (const char*)(Vp + (size_t)(h*NT + kt)*8192);
    char* kl = (char*)&Ks[b][0];
    char* vl = (char*)&Vt[b][0];
    #pragma unroll
    for (int p = 0; p < 4; ++p) gload_lds16(kg + lo + p*4096, kl + lo + p*4096);
    #pragma unroll
    for (int p = 0; p < 4; ++p) gload_lds16(vg + lo + p*4096, vl + lo + p*4096);
  };

  f32x4 acc[2][8];
  f32x4 acc_l[2];
  #pragma unroll
  for (int g = 0; g < 2; ++g) {
    #pragma unroll
    for (int i = 0; i < 8; ++i) acc[g][i] = (f32x4){0.f,0.f,0.f,0.f};
    acc_l[g] = (f32x4){0.f,0.f,0.f,0.f};
  }
  float m_run[2] = {-__builtin_inff(), -__builtin_inff()};

  issue(0, 0);
  issue(1, 1);
  asm volatile("s_waitcnt vmcnt(8)" ::: "memory");  // tile 0 arrived (8 of tile1 in flight)
  __builtin_amdgcn_s_barrier();
  __builtin_amdgcn_sched_barrier(0);

  // prologue QK(0) -> scA
  f32x4 scA[2][4], scB[2][4];
  {
    const char* KsB = (const char*)&Ks[0][0] + lo16;
    QK_COMPUTE(scA, KsB);
  }

  // NT-1 = 63 pipeline stages: 31 ping-pong pairs (kt=0..61) + 1 (kt=62), then tail
  for (int kt = 0; kt < NT-2; kt += 2) {
    BODY(scA, scB, kt,   0);
    BODY(scB, scA, kt+1, 1);
  }
  BODY(scA, scB, NT-2, 0);   // kt = 62: QK(63)->scB, SM+PV(62)

  // ---- tail tile NT-1 = 63: V hoist from buf[1] + softmax + PV (no more DMA) ----
  {
    bf16x8 vf[16];
    const char* VtB = (const char*)&Vt[1][0] + lo16;
    #pragma unroll
    for (int f = 0; f < 16; ++f) vf[f] = *(const bf16x8*)(VtB + (f << 10));
    asm volatile("s_waitcnt lgkmcnt(0)" ::: "memory");
    SOFTMAX_PV(scB);
  }

  // ---- epilogue: normalize, store O (lane: q=g*16+l16, d=db*16+lg*4+r) ----
  #pragma unroll
  for (int g = 0; g < 2; ++g) {
    const int qrow = qt*QB + wid*32 + g*16 + l16;
    const float inv = 1.0f / acc_l[g][0];
    float* op = Og + (size_t)qrow*HD + h*DD + lg*4;
    #pragma unroll
    for (int db = 0; db < 8; ++db) {
      float4 o;
      o.x = acc[g][db][0]*inv; o.y = acc[g][db][1]*inv;
      o.z = acc[g][db][2]*inv; o.w = acc[g][db][3]*inv;
      *(float4*)(op + db*16) = o;
    }
  }
}

extern "C" void kernel_launch(void* const* d_in, const int* in_sizes, int n_in,
                              void* d_out, int out_size, void* d_ws, size_t ws_size,
                              hipStream_t stream) {
  const float* Q = (const float*)d_in[0];
  const float* K = (const float*)d_in[1];
  const float* V = (const float*)d_in[2];
  float* O = (float*)d_out;
  bf16_t* Kp = (bf16_t*)d_ws;                       // 16.78 MB
  bf16_t* Vp = Kp + (size_t)NH*S_LEN*DD;            // 16.78 MB
  prep_kv<<<dim3(NT, NH, 2), 256, 0, stream>>>(K, V, Kp, Vp);
  attn_fwd<<<dim3(512), 256, 0, stream>>>(Q, Kp, Vp, O);
}